// Round 12
// baseline (204.942 us; speedup 1.0000x reference)
//
#include <hip/hip_runtime.h>
#include <hip/hip_bf16.h>

#define D 64
#define CLAMP_V -10000.0f
#define SBSHIFT 9           // super-bucket = 512 nodes (dst >> 9)
#define SBN 512
#define MAXSB 256           // static bound; runtime nbSB = ceil(100k/512) = 196
#define HCHUNK 4096         // edges per hist slice (inside prep)
#define SCHUNK 2048         // edges per scatter block (196 bins -> runs ~10)
#define NPW 8               // nodes per wave in seg_direct

typedef __bf16 bf16x4 __attribute__((ext_vector_type(4)));
typedef __bf16 bf16x8 __attribute__((ext_vector_type(8)));
typedef float floatx4 __attribute__((ext_vector_type(4)));
typedef unsigned short u16x2 __attribute__((ext_vector_type(2)));
typedef short s16x2 __attribute__((ext_vector_type(2)));

// packed max of 2x u16 (v_pk_max_u16)
__device__ __forceinline__ unsigned pkmax(unsigned a, unsigned b) {
    u16x2 r = __builtin_elementwise_max(__builtin_bit_cast(u16x2, a),
                                        __builtin_bit_cast(u16x2, b));
    return __builtin_bit_cast(unsigned, r);
}
// packed ord-encode of 2x bf16 (monotone u16): pos -> |0x8000, neg -> ~
__device__ __forceinline__ unsigned pk_ord_encode(unsigned g) {
    s16x2 t = __builtin_bit_cast(s16x2, g) >> 15;
    unsigned m = __builtin_bit_cast(unsigned, t) & 0x7FFF7FFFu;
    return g ^ (m | 0x80008000u);
}
__device__ __forceinline__ unsigned pk_ord_decode(unsigned e) {
    s16x2 t = __builtin_bit_cast(s16x2, e) >> 15;
    unsigned m = (~__builtin_bit_cast(unsigned, t)) & 0x7FFF7FFFu;
    return e ^ (m | 0x80008000u);
}

// ---------- pass 0: fp32->bf16 conversion + SB histogram + W frag layout ---
__global__ __launch_bounds__(256) void prep_kernel(
        const float* __restrict__ nf, __bf16* __restrict__ nf16, int n4,
        const int* __restrict__ dst, unsigned* __restrict__ ghist,
        int nE, int nbSB,
        const float* __restrict__ W, __bf16* __restrict__ wfrag,
        int histBlocks, int wBlock) {
    __shared__ unsigned h[MAXSB];
    int blk = blockIdx.x, t = threadIdx.x;
    int i = blk * 256 + t;
    if (i < n4) {
        float4 v = ((const float4*)nf)[i];
        bf16x4 o = { (__bf16)v.x, (__bf16)v.y, (__bf16)v.z, (__bf16)v.w };
        ((bf16x4*)nf16)[i] = o;
    }
    if (blk < histBlocks) {
        if (t < MAXSB) h[t] = 0;
        __syncthreads();
        int e0 = blk * HCHUNK;
        int ec = nE - e0; if (ec > HCHUNK) ec = HCHUNK;
        for (int k = t; k < ec; k += 256) atomicAdd(&h[dst[e0 + k] >> SBSHIFT], 1u);
        __syncthreads();
        if (t < (unsigned)nbSB && h[t]) atomicAdd(&ghist[t], h[t]);
    }
    if (blk == wBlock) {
        // W[k][n] fp32 -> bf16 in MFMA-fragment order:
        // fidx = ((ks*4+c)*64 + quad*16+l16)*8 + j, k=ks*32+quad*8+j, n=c*16+l16
        for (int idx = t; idx < 2 * D * D; idx += 256) {
            int k = idx >> 6, n = idx & 63;
            int ks = k >> 5, r = k & 31, quad = r >> 3, j = r & 7;
            int c = n >> 4, l16 = n & 15;
            int fidx = (((ks * 4 + c) * 64) + quad * 16 + l16) * 8 + j;
            wfrag[fidx] = (__bf16)W[idx];
        }
    }
}

// ---------- pass C: bin edges into 196 super-buckets, coalesced flush ------
// entry = (dst&511)<<17 | src  (src < 2^17).
// Each block recomputes the exclusive scan of ghist locally (deterministic)
// and reserves its global range via base + atomicAdd(cursor0) — no scan pass.
__global__ __launch_bounds__(256) void sb_scatter(
        const int* __restrict__ src, const int* __restrict__ dst,
        const unsigned* __restrict__ ghist, unsigned* __restrict__ cursor0,
        unsigned* __restrict__ packed, int nE, int nbSB) {
    __shared__ unsigned cop[MAXSB];            // cnt low16, off high16
    __shared__ unsigned short lb16[MAXSB];
    __shared__ unsigned gbase[MAXSB];
    __shared__ unsigned payload[SCHUNK];       // 8 KB, bucket-sorted entries
    __shared__ unsigned char sbid[SCHUNK];     // 2 KB
    __shared__ unsigned ts[256];
    int t = threadIdx.x;
    int e0 = blockIdx.x * SCHUNK;
    int ec = nE - e0; if (ec > SCHUNK) ec = SCHUNK;

    // local exclusive scan of ghist -> per-bucket global base
    unsigned g = (t < nbSB) ? ghist[t] : 0u;
    ts[t] = g; __syncthreads();
    for (int o = 1; o < 256; o <<= 1) {
        unsigned x = (t >= o) ? ts[t - o] : 0u;
        __syncthreads();
        ts[t] += x;
        __syncthreads();
    }
    unsigned myBase = ts[t] - g;               // exclusive prefix (t < nbSB)

    if (t < MAXSB) cop[t] = 0;
    __syncthreads();
    for (int i = t; i < ec; i += 256)
        atomicAdd(&cop[dst[e0 + i] >> SBSHIFT], 1u);
    __syncthreads();
    unsigned c = (t < nbSB) ? (cop[t] & 0xFFFFu) : 0u;
    ts[t] = c; __syncthreads();
    for (int o = 1; o < 256; o <<= 1) {
        unsigned x = (t >= o) ? ts[t - o] : 0u;
        __syncthreads();
        ts[t] += x;
        __syncthreads();
    }
    if (t < nbSB) {
        lb16[t] = (unsigned short)(ts[t] - c);
        if (c) gbase[t] = myBase + atomicAdd(&cursor0[t], c);
    }
    __syncthreads();
    for (int i = t; i < ec; i += 256) {
        int e = e0 + i;
        int d = dst[e];
        int b = d >> SBSHIFT;
        unsigned p = atomicAdd(&cop[b], 0x10000u) >> 16;
        unsigned pos = (unsigned)lb16[b] + p;
        payload[pos] = ((unsigned)(d & (SBN - 1)) << 17) | (unsigned)src[e];
        sbid[pos] = (unsigned char)b;
    }
    __syncthreads();
    // flush: payload is bucket-sorted; same-bucket entries are adjacent ->
    // runs of ~10 entries -> line-coalesced bursts
    for (int i = t; i < ec; i += 256) {
        unsigned b = sbid[i];
        packed[gbase[b] + ((unsigned)i - (unsigned)lb16[b])] = payload[i];
    }
}

// ---------- pass C2: per-SB counting sort to node order + CSR nodestart ----
// 4 blocks per SB: each counts the full SB range binned by quarter, scans
// totals -> nodestart (q==0 writes), scatters only its own quarter with
// base = nodestart + prefix of earlier quarters' counts.
__global__ __launch_bounds__(256) void sb_sort(
        const unsigned* __restrict__ packed1, const unsigned* __restrict__ ghist,
        unsigned* __restrict__ packed2, unsigned* __restrict__ nodestart,
        int nbSB, int nN) {
    __shared__ unsigned cnt[4][SBN];            // 8 KB
    __shared__ unsigned cur[SBN];               // 2 KB
    __shared__ unsigned ts[256];
    int blk = blockIdx.x;
    int sb = blk >> 2, q = blk & 3;
    int t = threadIdx.x;

    // local scan of ghist -> beg/end of this SB
    unsigned g = (t < nbSB) ? ghist[t] : 0u;
    ts[t] = g; __syncthreads();
    for (int o = 1; o < 256; o <<= 1) {
        unsigned x = (t >= o) ? ts[t - o] : 0u;
        __syncthreads();
        ts[t] += x;
        __syncthreads();
    }
    __shared__ unsigned sBegEnd[2];
    if (t == sb) { sBegEnd[0] = ts[t] - g; sBegEnd[1] = ts[t]; }
    __syncthreads();
    unsigned beg = sBegEnd[0], end = sBegEnd[1];
    unsigned len = end - beg;
    unsigned qlen = (len + 3) >> 2;

    for (int i = t; i < 4 * SBN; i += 256) ((unsigned*)cnt)[i] = 0;
    __syncthreads();
    // count full range, binned by quarter
    for (unsigned i = beg + t; i < end; i += 256) {
        unsigned e = packed1[i];
        unsigned r = i - beg;
        unsigned qq = (r >= qlen) + (r >= 2 * qlen) + (r >= 3 * qlen);
        atomicAdd(&cnt[qq][e >> 17], 1u);
    }
    __syncthreads();
    // per-node totals (thread owns nodes 2t, 2t+1), block scan -> nodestart
    unsigned a0 = cnt[0][2 * t] + cnt[1][2 * t] + cnt[2][2 * t] + cnt[3][2 * t];
    unsigned a1 = cnt[0][2 * t + 1] + cnt[1][2 * t + 1]
                + cnt[2][2 * t + 1] + cnt[3][2 * t + 1];
    unsigned s = a0 + a1;
    ts[t] = s; __syncthreads();
    for (int o = 1; o < 256; o <<= 1) {
        unsigned x = (t >= o) ? ts[t - o] : 0u;
        __syncthreads();
        ts[t] += x;
        __syncthreads();
    }
    unsigned ex = ts[t] - s;
    int n0 = sb * SBN;
    if (q == 0) {
        if (n0 + 2 * t     <= nN) nodestart[n0 + 2 * t]     = beg + ex;
        if (n0 + 2 * t + 1 <= nN) nodestart[n0 + 2 * t + 1] = beg + ex + a0;
    }
    // cursor base for OUR quarter: nodestart + prefix of earlier quarters
    unsigned p0 = 0, p1 = 0;
    for (int p = 0; p < 4; ++p) {
        if (p < q) { p0 += cnt[p][2 * t]; p1 += cnt[p][2 * t + 1]; }
    }
    cur[2 * t]     = beg + ex + p0;
    cur[2 * t + 1] = beg + ex + a0 + p1;
    __syncthreads();
    // scatter own quarter (writes confined to this SB's ~32 KB window)
    unsigned qb = beg + q * qlen;
    unsigned qe = qb + qlen; if (qe > end) qe = end;
    for (unsigned i = qb + t; i < qe; i += 256) {
        unsigned e = packed1[i];
        unsigned p = atomicAdd(&cur[e >> 17], 1u);
        packed2[p] = e & 0x1FFFFu;      // src only; position encodes node
    }
}

// ---------- pass D: direct segmax over CSR runs; zero LDS ----------
// wave owns NPW consecutive nodes; per node: coalesced run prefetch +
// shfl-broadcast, up to 16 edges/iter (8 gathers in flight), 2 packed
// dims/lane register max.
// NOTE: every __shfl must execute with ALL 64 lanes active — ds_bpermute
// data from exec-masked source lanes is undefined (R9 bug). Tails clamp
// the index (dup edge; max idempotent) to stay convergent.
__global__ __launch_bounds__(256) void seg_direct(
        const unsigned* __restrict__ nfu,       // nf16 as dwords, 32/row
        const unsigned* __restrict__ packed2,   // node-sorted src indices
        const unsigned* __restrict__ nodestart,
        unsigned* __restrict__ agg16u,          // bf16 agg as dwords, 32/row
        int nN) {
    int t = threadIdx.x;
    int wv = t >> 6, ln = t & 63;
    int half = ln >> 5, dln = ln & 31;
    int n0 = blockIdx.x * (4 * NPW) + wv * NPW;
    #pragma unroll 1
    for (int k = 0; k < NPW; ++k) {
        int n = n0 + k;                          // wave-uniform
        if (n >= nN) break;
        unsigned rb = nodestart[n], re = nodestart[n + 1];
        unsigned m0 = 0, m1 = 0, m2 = 0, m3 = 0;
        for (unsigned c = rb; c < re; c += 64) {
            unsigned idx = c + (unsigned)ln;
            unsigned pe = (idx < re) ? packed2[idx] : 0u;
            int lim = (int)(re - c); if (lim > 64) lim = 64;
            int j = 0;
            for (; j + 16 <= lim; j += 16) {
                unsigned s0 = __shfl(pe, j + half, 64);
                unsigned s1 = __shfl(pe, j + 2 + half, 64);
                unsigned s2 = __shfl(pe, j + 4 + half, 64);
                unsigned s3 = __shfl(pe, j + 6 + half, 64);
                unsigned s4 = __shfl(pe, j + 8 + half, 64);
                unsigned s5 = __shfl(pe, j + 10 + half, 64);
                unsigned s6 = __shfl(pe, j + 12 + half, 64);
                unsigned s7 = __shfl(pe, j + 14 + half, 64);
                unsigned g0 = nfu[(size_t)s0 * 32 + dln];
                unsigned g1 = nfu[(size_t)s1 * 32 + dln];
                unsigned g2 = nfu[(size_t)s2 * 32 + dln];
                unsigned g3 = nfu[(size_t)s3 * 32 + dln];
                unsigned g4 = nfu[(size_t)s4 * 32 + dln];
                unsigned g5 = nfu[(size_t)s5 * 32 + dln];
                unsigned g6 = nfu[(size_t)s6 * 32 + dln];
                unsigned g7 = nfu[(size_t)s7 * 32 + dln];
                m0 = pkmax(m0, pk_ord_encode(g0));
                m1 = pkmax(m1, pk_ord_encode(g1));
                m2 = pkmax(m2, pk_ord_encode(g2));
                m3 = pkmax(m3, pk_ord_encode(g3));
                m0 = pkmax(m0, pk_ord_encode(g4));
                m1 = pkmax(m1, pk_ord_encode(g5));
                m2 = pkmax(m2, pk_ord_encode(g6));
                m3 = pkmax(m3, pk_ord_encode(g7));
            }
            for (; j + 8 <= lim; j += 8) {
                unsigned s0 = __shfl(pe, j + half, 64);
                unsigned s1 = __shfl(pe, j + 2 + half, 64);
                unsigned s2 = __shfl(pe, j + 4 + half, 64);
                unsigned s3 = __shfl(pe, j + 6 + half, 64);
                unsigned g0 = nfu[(size_t)s0 * 32 + dln];
                unsigned g1 = nfu[(size_t)s1 * 32 + dln];
                unsigned g2 = nfu[(size_t)s2 * 32 + dln];
                unsigned g3 = nfu[(size_t)s3 * 32 + dln];
                m0 = pkmax(m0, pk_ord_encode(g0));
                m1 = pkmax(m1, pk_ord_encode(g1));
                m2 = pkmax(m2, pk_ord_encode(g2));
                m3 = pkmax(m3, pk_ord_encode(g3));
            }
            for (; j + 4 <= lim; j += 4) {
                unsigned s0 = __shfl(pe, j + half, 64);
                unsigned s1 = __shfl(pe, j + 2 + half, 64);
                unsigned g0 = nfu[(size_t)s0 * 32 + dln];
                unsigned g1 = nfu[(size_t)s1 * 32 + dln];
                m0 = pkmax(m0, pk_ord_encode(g0));
                m1 = pkmax(m1, pk_ord_encode(g1));
            }
            for (; j < lim; j += 2) {
                int jj = j + half;
                if (jj >= lim) jj = lim - 1;    // dup tail, convergent shfl
                unsigned g = nfu[(size_t)__shfl(pe, jj, 64) * 32 + dln];
                m0 = pkmax(m0, pk_ord_encode(g));
            }
        }
        unsigned m = pkmax(pkmax(m0, m1), pkmax(m2, m3));
        m = pkmax(m, __shfl_xor(m, 32, 64));    // cross-half merge
        if (ln < 32) {
            unsigned raw = pk_ord_decode(m);    // empty run -> NaN halves
            unsigned xr  = nfu[(size_t)n * 32 + dln];
            float v0 = __uint_as_float(raw << 16);
            float v1 = __uint_as_float(raw & 0xFFFF0000u);
            float x0 = __uint_as_float(xr << 16);
            float x1 = __uint_as_float(xr & 0xFFFF0000u);
            float r0 = v0 - x0; r0 = (r0 >= CLAMP_V) ? r0 : 0.0f;  // NaN -> 0
            float r1 = v1 - x1; r1 = (r1 >= CLAMP_V) ? r1 : 0.0f;
            __bf16 b0 = (__bf16)r0, b1 = (__bf16)r1;
            unsigned o = ((unsigned)__builtin_bit_cast(unsigned short, b1) << 16)
                       |  (unsigned)__builtin_bit_cast(unsigned short, b0);
            agg16u[(size_t)n * 32 + dln] = o;
        }
    }
}

// ---------- pass E: MFMA MLP; W from frag-order buffer ----------
__global__ __launch_bounds__(256) void node_mlp_mfma(
        const __bf16* __restrict__ nf16,
        const __bf16* __restrict__ agg16,
        float* __restrict__ out,
        const __bf16* __restrict__ wfrag,
        const float* __restrict__ bias,
        int nTiles, int nN) {
    int lane = threadIdx.x & 63;
    int quad = lane >> 4;
    int l16  = lane & 15;
    int waveGlobal = blockIdx.x * 4 + (threadIdx.x >> 6);
    int nWaves = gridDim.x * 4;

    bf16x8 bfrag[4][4];
    #pragma unroll
    for (int c = 0; c < 4; ++c)
        #pragma unroll
        for (int ks = 0; ks < 4; ++ks)
            bfrag[c][ks] = *(const bf16x8*)(wfrag + ((size_t)((ks * 4 + c) * 64 + lane)) * 8);
    float bv[4];
    #pragma unroll
    for (int c = 0; c < 4; ++c) bv[c] = bias[c * 16 + l16];

    for (int t = waveGlobal; t < nTiles; t += nWaves) {
        int n0 = t * 16;
        int rowA = n0 + l16;
        if (rowA >= nN) rowA = nN - 1;
        const __bf16* nfr = nf16  + (size_t)rowA * D;
        const __bf16* agr = agg16 + (size_t)rowA * D;

        floatx4 acc[4] = {{0,0,0,0},{0,0,0,0},{0,0,0,0},{0,0,0,0}};
        #pragma unroll
        for (int ks = 0; ks < 4; ++ks) {
            const __bf16* p = (ks < 2) ? (nfr + ks * 32 + quad * 8)
                                       : (agr + (ks - 2) * 32 + quad * 8);
            bf16x8 a = *(const bf16x8*)p;
            #pragma unroll
            for (int c = 0; c < 4; ++c)
                acc[c] = __builtin_amdgcn_mfma_f32_16x16x32_bf16(
                             a, bfrag[c][ks], acc[c], 0, 0, 0);
        }
        #pragma unroll
        for (int r = 0; r < 4; ++r) {
            int row = n0 + quad * 4 + r;
            if (row < nN) {
                #pragma unroll
                for (int c = 0; c < 4; ++c) {
                    float vv = acc[c][r] + bv[c];
                    out[(size_t)row * D + c * 16 + l16] = fmaxf(vv, 0.0f);
                }
            }
        }
    }
}

extern "C" void kernel_launch(void* const* d_in, const int* in_sizes, int n_in,
                              void* d_out, int out_size, void* d_ws, size_t ws_size,
                              hipStream_t stream) {
    const float* nf  = (const float*)d_in[0];
    const int*   src = (const int*)d_in[1];
    const int*   dst = (const int*)d_in[2];
    const float* W   = (const float*)d_in[3];
    const float* b   = (const float*)d_in[4];
    float* out = (float*)d_out;

    int nN = in_sizes[0] / D;
    int nE = in_sizes[1];
    int nbSB = (nN + SBN - 1) / SBN;            // 196

    // ws layout
    char* wsb = (char*)d_ws;
    size_t nfB  = (((size_t)nN * D * 2) + 255) & ~(size_t)255;  // 12.8 MB
    size_t pkB  = (((size_t)nE * 4)     + 255) & ~(size_t)255;  // 6.4 MB
    __bf16*   nf16    = (__bf16*)wsb;
    __bf16*   agg16   = (__bf16*)(wsb + nfB);
    unsigned* packed1 = (unsigned*)(wsb + 2 * nfB);
    unsigned* ghist   = (unsigned*)(wsb + 2 * nfB + pkB);            // MAXSB
    unsigned* cursor0 = (unsigned*)(wsb + 2 * nfB + pkB + 4 * MAXSB);// MAXSB
    __bf16*   wfrag   = (__bf16*)(wsb + 2 * nfB + pkB + 8 * MAXSB);
    unsigned* nodestart = (unsigned*)(wsb + 2 * nfB + pkB + 8 * MAXSB + 32768);
    // packed2 lives in d_out: consumed by seg_direct before the MLP writes out
    unsigned* packed2 = (unsigned*)d_out;

    // zeroes ghist AND cursor0 (adjacent)
    hipMemsetAsync(ghist, 0, 8 * MAXSB, stream);

    int n4 = nN * D / 4;                        // 1.6M
    int convBlocks = (n4 + 255) / 256;          // 6250
    int histBlocks = (nE + HCHUNK - 1) / HCHUNK;// 391
    int gridPrep = convBlocks > histBlocks ? convBlocks : histBlocks;
    prep_kernel<<<gridPrep, 256, 0, stream>>>(nf, nf16, n4, dst, ghist, nE, nbSB,
                                              W, wfrag, histBlocks, gridPrep - 1);

    int nbS = (nE + SCHUNK - 1) / SCHUNK;       // 782
    sb_scatter<<<nbS, 256, 0, stream>>>(src, dst, ghist, cursor0, packed1, nE, nbSB);

    sb_sort<<<nbSB * 4, 256, 0, stream>>>(packed1, ghist, packed2, nodestart,
                                          nbSB, nN);

    int segBlocks = (nN + 4 * NPW - 1) / (4 * NPW);   // 3125
    seg_direct<<<segBlocks, 256, 0, stream>>>(
        (const unsigned*)nf16, packed2, nodestart, (unsigned*)agg16, nN);

    int nTiles = (nN + 15) / 16;
    node_mlp_mfma<<<768, 256, 0, stream>>>(nf16, agg16, out, wfrag, b, nTiles, nN);
}